// Round 13
// baseline (20513.974 us; speedup 1.0000x reference)
//
#include <hip/hip_runtime.h>
#include <stdint.h>
#include <stddef.h>

// ---------------- problem constants ----------------
static constexpr int  T_STEPS   = 2048;
static constexpr int  BATCH     = 16;
static constexpr int  DIM       = 1024;
static constexpr long RROWS     = (long)T_STEPS * BATCH;   // 32768 rows of x
static constexpr long BD        = (long)BATCH * DIM;       // 16384
static constexpr long OUT_ELEMS = (long)T_STEPS * BD;      // 33554432

// ---------------- ws layout (bytes) ----------------
static constexpr size_t WX_OFF  = 0;
static constexpr size_t XBF_OFF = 134217728;
static constexpr size_t WHI_OFF = XBF_OFF + 67108864;   // 201326592
static constexpr size_t WLO_OFF = WHI_OFF + 6291456;    // 207618048
static constexpr size_t HBP_OFF = WLO_OFF + 6291456;    // 213909504: packed h [2][B][D/2] u32 (64KB)

typedef __attribute__((ext_vector_type(2))) float          f32x2;
typedef __attribute__((ext_vector_type(4))) float          f32x4;
typedef __attribute__((ext_vector_type(8))) short          s16x8;
typedef __attribute__((ext_vector_type(4))) unsigned short u16x4;
typedef __attribute__((ext_vector_type(8))) unsigned short u16x8;

#define AS1 __attribute__((address_space(1)))
#define AS3 __attribute__((address_space(3)))

// ---------------- helpers ----------------
static __device__ __forceinline__ unsigned short f2bf(float x) {
  union { float f; unsigned u; } a; a.f = x;
  unsigned r = a.u + 0x7fffu + ((a.u >> 16) & 1u);
  return (unsigned short)(r >> 16);
}
static __device__ __forceinline__ float bf2f(unsigned short h) {
  union { unsigned u; float f; } a; a.u = ((unsigned)h) << 16; return a.f;
}
static __device__ __forceinline__ void gload_lds16(const void* g, void* l) {
  __builtin_amdgcn_global_load_lds((const AS1 void*)g, (AS3 void*)l, 16, 0, 0);
}
static __device__ __forceinline__ float fast_tanh(float z) {
  return 1.0f - 2.0f / (__expf(2.0f * z) + 1.0f);
}

// ---------------- convert x -> bf16 ----------------
__global__ __launch_bounds__(256) void convert_x_kernel(const float* __restrict__ x,
                                                        unsigned short* __restrict__ xbf) {
  const long n8 = (RROWS * DIM) / 8;
  const long stride = (long)gridDim.x * blockDim.x;
  for (long i = (long)blockIdx.x * blockDim.x + threadIdx.x; i < n8; i += stride) {
    const float4* p = (const float4*)(x + i * 8);
    float4 v0 = p[0], v1 = p[1];
    u16x8 o;
    o[0] = f2bf(v0.x); o[1] = f2bf(v0.y); o[2] = f2bf(v0.z); o[3] = f2bf(v0.w);
    o[4] = f2bf(v1.x); o[5] = f2bf(v1.y); o[6] = f2bf(v1.z); o[7] = f2bf(v1.w);
    *(u16x8*)(xbf + i * 8) = o;
  }
}

// ---------------- convert [W_alpha;W_beta;W_x] -> bf16 hi/lo split ----------------
__global__ __launch_bounds__(256) void convert_w_kernel(const float* __restrict__ Wa,
                                                        const float* __restrict__ Wb,
                                                        const float* __restrict__ Wx,
                                                        unsigned short* __restrict__ whi,
                                                        unsigned short* __restrict__ wlo) {
  const long n4 = (3l * 1024 * 1024) / 4;
  const long stride = (long)gridDim.x * blockDim.x;
  for (long i = (long)blockIdx.x * blockDim.x + threadIdx.x; i < n4; i += stride) {
    long e = i * 4;
    int mat = (int)(e >> 20);
    long off = e & 1048575l;
    const float* src = (mat == 0) ? Wa : (mat == 1) ? Wb : Wx;
    float4 v = *(const float4*)(src + off);
    u16x4 hi, lo;
    hi[0] = f2bf(v.x); lo[0] = f2bf(v.x - bf2f(hi[0]));
    hi[1] = f2bf(v.y); lo[1] = f2bf(v.y - bf2f(hi[1]));
    hi[2] = f2bf(v.z); lo[2] = f2bf(v.z - bf2f(hi[2]));
    hi[3] = f2bf(v.w); lo[3] = f2bf(v.w - bf2f(hi[3]));
    *(u16x4*)(whi + e) = hi;
    *(u16x4*)(wlo + e) = lo;
  }
}

// ---------------- fused pre-GEMM: alpha/beta/wx = act(x @ Wcat^T + bias) ----------------
__global__ __launch_bounds__(256) void gemm_pre(
    const unsigned short* __restrict__ xbf,
    const unsigned short* __restrict__ whi,
    const unsigned short* __restrict__ wlo,
    const float* __restrict__ b_alpha, const float* __restrict__ b_beta, const float* __restrict__ b_x,
    float* __restrict__ alpha_dst, float* __restrict__ beta_dst, float* __restrict__ wx_dst)
{
  __shared__ unsigned short Al[128 * 64];
  __shared__ unsigned short Bh[128 * 64];
  __shared__ unsigned short Bl[128 * 64];
  const int tid  = threadIdx.x;
  const int lane = tid & 63;
  const int w    = tid >> 6;
  const int wm   = w >> 1, wn = w & 1;
  const long rowA0 = (long)blockIdx.x * 128;
  const int  colB0 = blockIdx.y * 128;

  f32x4 acc[4][4];
#pragma unroll
  for (int i = 0; i < 4; ++i)
#pragma unroll
    for (int j = 0; j < 4; ++j) acc[i][j] = (f32x4){0.f, 0.f, 0.f, 0.f};

  for (int k0 = 0; k0 < 1024; k0 += 64) {
#pragma unroll
    for (int is = 0; is < 4; ++is) {
      const int o   = is * 4096 + tid * 16;
      const int row = o >> 7;
      const int ke  = (o & 127) >> 1;
      const long asrc = (rowA0 + row) * 1024 + (k0 + ke);
      const long bsrc = ((long)(colB0 + row)) * 1024 + (k0 + ke);
      gload_lds16(xbf + asrc, (char*)Al + is * 4096 + w * 1024);
      gload_lds16(whi + bsrc, (char*)Bh + is * 4096 + w * 1024);
      gload_lds16(wlo + bsrc, (char*)Bl + is * 4096 + w * 1024);
    }
    asm volatile("s_waitcnt vmcnt(0)" ::: "memory");
    __syncthreads();
#pragma unroll
    for (int kk = 0; kk < 2; ++kk) {
      const int koff = kk * 64 + ((lane >> 4) * 16);
      s16x8 a[4], bhf[4], blf[4];
#pragma unroll
      for (int i = 0; i < 4; ++i)
        a[i] = *(const s16x8*)((const char*)Al + (wm * 64 + i * 16 + (lane & 15)) * 128 + koff);
#pragma unroll
      for (int j = 0; j < 4; ++j) {
        const int r = (wn * 64 + j * 16 + (lane & 15)) * 128 + koff;
        bhf[j] = *(const s16x8*)((const char*)Bh + r);
        blf[j] = *(const s16x8*)((const char*)Bl + r);
      }
#pragma unroll
      for (int i = 0; i < 4; ++i)
#pragma unroll
        for (int j = 0; j < 4; ++j) {
          acc[i][j] = __builtin_amdgcn_mfma_f32_16x16x32_bf16(a[i], bhf[j], acc[i][j], 0, 0, 0);
          acc[i][j] = __builtin_amdgcn_mfma_f32_16x16x32_bf16(a[i], blf[j], acc[i][j], 0, 0, 0);
        }
    }
    __syncthreads();
  }

  const int region = colB0 >> 10;
  const float* bias = (region == 0) ? b_alpha : (region == 1) ? b_beta : b_x;
  float* dst = (region == 0) ? alpha_dst : (region == 1) ? beta_dst : wx_dst;
#pragma unroll
  for (int j = 0; j < 4; ++j) {
    const int colg = colB0 + wn * 64 + j * 16 + (lane & 15);
    const int nl = colg & 1023;
    const float bj = bias[nl];
#pragma unroll
    for (int i = 0; i < 4; ++i) {
#pragma unroll
      for (int r = 0; r < 4; ++r) {
        const long rowg = rowA0 + wm * 64 + i * 16 + ((lane >> 4) * 4) + r;
        float z = acc[i][j][r] + bj;
        float val = (region == 2) ? z : (1.0f / (1.0f + __expf(-z)));
        dst[rowg * 1024 + nl] = val;
      }
    }
  }
}

// ---------------- persistent scan: barrier-free autonomous waves ----------------
// 32 WGs; waves 1-3 only stage W into LDS then retire; wave 0 owns channels
// [wg*32, wg*32+32) with FULL K=1024 -> no cross-wave reduction, no zred LDS,
// no __syncthreads in the step loop. Wire protocol identical to round 12:
// word = {bf16(h[ch1]) << 16 | bf16(h[ch0]) LSB=epoch (t>>1)&1} in buf[t&1],
// agent-scope relaxed atomics; mod-4 discrimination, drift bound by the
// consume-before-publish dependency chain. Per step the wave sweeps all 32
// k-chunks branch-free (64 u64), MFMAs fresh chunks into 4 acc chains, retries
// only pending chunks (issue-all-then-check). Elementwise update runs directly
// on the MFMA C layout (lane owns b=(lane>>4)*4+r, ch=n0+j*16+(lane&15));
// publish pairs channels via one shfl_xor(1): even lanes store j=0 words, odd
// lanes j=1. NT outputs deferred one step so HBM acks never gate sweep waits.
__global__ __launch_bounds__(256, 1) void scan_kernel(
    const float* __restrict__ Wh,
    const float* __restrict__ h0,
    const float* __restrict__ wxb,
    float* __restrict__ out_buf,     // d_out: beta pre-stored here
    float* __restrict__ h_out,       // d_out + OUT_ELEMS: alpha pre-stored at +BD
    unsigned* __restrict__ hbp)      // packed h ping-pong [2][B][D/2] u32
{
  __shared__ unsigned short WhiL[32 * 1024];
  __shared__ unsigned short WloL[32 * 1024];

  const int tid = threadIdx.x;
  const int wg  = blockIdx.x;
  const int n0  = wg * 32;

  // ---- stage W_h slice (32 rows) into LDS, hi/lo bf16, XOR-swizzled (256 thr) ----
  {
    const int row = tid >> 3;            // 0..31
    const int kb  = (tid & 7) * 128;     // 128 elems per thread
    const float* src = Wh + (size_t)(n0 + row) * 1024 + kb;
    const unsigned sx = ((unsigned)(row & 7)) << 4;
    const unsigned rb = (unsigned)row * 2048u;
#pragma unroll
    for (int q = 0; q < 32; ++q) {
      float4 v = *(const float4*)(src + q * 4);
      u16x4 hi, lo;
      hi[0] = f2bf(v.x); lo[0] = f2bf(v.x - bf2f(hi[0]));
      hi[1] = f2bf(v.y); lo[1] = f2bf(v.y - bf2f(hi[1]));
      hi[2] = f2bf(v.z); lo[2] = f2bf(v.z - bf2f(hi[2]));
      hi[3] = f2bf(v.w); lo[3] = f2bf(v.w - bf2f(hi[3]));
      const unsigned addr = (rb + (unsigned)(kb + q * 4) * 2u) ^ sx;
      *(u16x4*)((char*)WhiL + addr) = hi;
      *(u16x4*)((char*)WloL + addr) = lo;
    }
  }
  __syncthreads();        // last barrier — W staged
  if (tid >= 64) return;  // waves 1-3 retire; wave 0 runs the scan barrier-free

  const int lane = tid;
  const int arow = lane & 15;        // wire A-row (batch) / W-col (channel) index
  const int gk   = lane >> 4;        // k subgroup
  const unsigned bswz = ((unsigned)(arow & 7)) << 4;

  // elementwise ownership (MFMA C layout): b = gk*4 + r, ch = n0 + j*16 + arow
  const int gbase = gk * 4096 + n0 + arow;              // + r*1024 + j*16
  const int jst   = lane & 1;                           // this lane stores j=jst words
  const int pbase = gk * 2048 + (n0 >> 1) + jst * 8 + (arow >> 1);   // + r*512

  // ---- t=0: h[0]=h0, write h_out plane 0, publish (eps 0, buf 0) ----
  float hp[4][2];
#pragma unroll
  for (int r = 0; r < 4; ++r)
#pragma unroll
    for (int j = 0; j < 2; ++j) {
      hp[r][j] = h0[gbase + r * 1024 + j * 16];
      h_out[gbase + r * 1024 + j * 16] = hp[r][j];
    }
#pragma unroll
  for (int r = 0; r < 4; ++r) {
    unsigned e0 = f2bf(hp[r][0]);
    unsigned e1 = f2bf(hp[r][1]);
    unsigned p0 = (unsigned)__shfl_xor((int)e0, 1);
    unsigned p1 = (unsigned)__shfl_xor((int)e1, 1);
    unsigned wv = jst ? ((e1 << 16) | (p1 & 0xFFFEu))
                      : ((p0 << 16) | (e0 & 0xFFFEu));
    __hip_atomic_store(hbp + pbase + r * 512, wv,
                       __ATOMIC_RELAXED, __HIP_MEMORY_SCOPE_AGENT);
  }

  // gates for t=0 (alpha pre-stored in h[t+1] slots, beta in out[t] slots)
  float a_c[4][2], b_c[4][2], w_c[4][2];
#pragma unroll
  for (int r = 0; r < 4; ++r)
#pragma unroll
    for (int j = 0; j < 2; ++j) {
      const int o = gbase + r * 1024 + j * 16;
      a_c[r][j] = h_out[BD + o];
      b_c[r][j] = out_buf[o];
      w_c[r][j] = wxb[o];
    }

  float dh[4][2];   // deferred outputs (step t stored during step t+1)
#pragma unroll
  for (int r = 0; r < 4; ++r) { dh[r][0] = 0.f; dh[r][1] = 0.f; }

  for (int t = 0; t < T_STEPS; ++t) {
    const unsigned eps = (unsigned)((t >> 1) & 1);
    // chunk c (c=0..31): lane reads h[b=arow][k=c*32+gk*8 .. +8] = 2 u64
    const unsigned long long* base64 =
        (const unsigned long long*)hbp + (size_t)(t & 1) * 4096 + arow * 256 + gk * 2;

    // ---- first sweep: issue ALL 32 chunks branch-free ----
    unsigned long long vv[32][2];
#pragma unroll
    for (int c = 0; c < 32; ++c) {
      vv[c][0] = __hip_atomic_load(base64 + c * 8,     __ATOMIC_RELAXED, __HIP_MEMORY_SCOPE_AGENT);
      vv[c][1] = __hip_atomic_load(base64 + c * 8 + 1, __ATOMIC_RELAXED, __HIP_MEMORY_SCOPE_AGENT);
    }

    // prefetch next step's gates (NT, younger than sweep loads)
    float a_n[4][2], b_n[4][2], w_n[4][2];
    if (t + 1 < T_STEPS) {
      const long o = (long)(t + 1) * BD + gbase;
#pragma unroll
      for (int r = 0; r < 4; ++r)
#pragma unroll
        for (int j = 0; j < 2; ++j) {
          const long oo = o + r * 1024 + j * 16;
          a_n[r][j] = __builtin_nontemporal_load(h_out + BD + oo);
          b_n[r][j] = __builtin_nontemporal_load(out_buf + oo);
          w_n[r][j] = __builtin_nontemporal_load(wxb + oo);
        }
    } else {
#pragma unroll
      for (int r = 0; r < 4; ++r)
#pragma unroll
        for (int j = 0; j < 2; ++j) { a_n[r][j] = 0.f; b_n[r][j] = 0.f; w_n[r][j] = 0.f; }
    }
    __builtin_amdgcn_sched_barrier(0);

    // ---- deferred NT output stores for step t-1 (youngest vmem ops) ----
    if (t > 0) {
      const long od = (long)(t - 1) * BD + gbase;
#pragma unroll
      for (int r = 0; r < 4; ++r)
#pragma unroll
        for (int j = 0; j < 2; ++j) {
          const long oo = od + r * 1024 + j * 16;
          const float d = dh[r][j];
          __builtin_nontemporal_store(d, h_out + BD + oo);
          const float sg = 1.0f / (1.0f + __expf(-d));
          __builtin_nontemporal_store(d * d * sg, out_buf + oo);
        }
    }

    // 4 accumulator chains: ac[j][chunk parity]
    f32x4 ac[2][2];
    ac[0][0] = (f32x4){0.f,0.f,0.f,0.f}; ac[0][1] = (f32x4){0.f,0.f,0.f,0.f};
    ac[1][0] = (f32x4){0.f,0.f,0.f,0.f}; ac[1][1] = (f32x4){0.f,0.f,0.f,0.f};
    union Frag { unsigned long long u[2]; s16x8 h; };

#define DO_CHUNK(C, V)                                                            \
    {                                                                             \
      Frag fh; fh.u[0] = (V)[0]; fh.u[1] = (V)[1];                                \
      const unsigned kb = (unsigned)(C) * 64u + (unsigned)gk * 16u;               \
      const unsigned a0 = ((unsigned)arow * 2048u + kb) ^ bswz;                   \
      const unsigned a1 = ((unsigned)(16 + arow) * 2048u + kb) ^ bswz;            \
      s16x8 bh0 = *(const s16x8*)((const char*)WhiL + a0);                        \
      s16x8 bl0 = *(const s16x8*)((const char*)WloL + a0);                        \
      s16x8 bh1 = *(const s16x8*)((const char*)WhiL + a1);                        \
      s16x8 bl1 = *(const s16x8*)((const char*)WloL + a1);                        \
      ac[0][(C) & 1] = __builtin_amdgcn_mfma_f32_16x16x32_bf16(fh.h, bh0, ac[0][(C) & 1], 0, 0, 0); \
      ac[0][(C) & 1] = __builtin_amdgcn_mfma_f32_16x16x32_bf16(fh.h, bl0, ac[0][(C) & 1], 0, 0, 0); \
      ac[1][(C) & 1] = __builtin_amdgcn_mfma_f32_16x16x32_bf16(fh.h, bh1, ac[1][(C) & 1], 0, 0, 0); \
      ac[1][(C) & 1] = __builtin_amdgcn_mfma_f32_16x16x32_bf16(fh.h, bl1, ac[1][(C) & 1], 0, 0, 0); \
    }

    // ---- verify (epoch LSB on even-channel halves) + MFMA fresh chunks ----
    unsigned pend = 0;
#pragma unroll
    for (int c = 0; c < 32; ++c) {
      unsigned bad = ((unsigned)vv[c][0] ^ eps) & 1u;
      bad |= ((unsigned)(vv[c][0] >> 32) ^ eps) & 1u;
      bad |= ((unsigned)vv[c][1] ^ eps) & 1u;
      bad |= ((unsigned)(vv[c][1] >> 32) ^ eps) & 1u;
      if (__all(bad == 0u)) { DO_CHUNK(c, vv[c]); }
      else                  { pend |= 1u << c; }
    }

    // ---- retry sweeps: pending-only, issue-all-then-check ----
    int iters = 0;
    while (pend) {
#pragma unroll
      for (int c = 0; c < 32; ++c)
        if (pend & (1u << c)) {
          vv[c][0] = __hip_atomic_load(base64 + c * 8,     __ATOMIC_RELAXED, __HIP_MEMORY_SCOPE_AGENT);
          vv[c][1] = __hip_atomic_load(base64 + c * 8 + 1, __ATOMIC_RELAXED, __HIP_MEMORY_SCOPE_AGENT);
        }
      __builtin_amdgcn_sched_barrier(0);
#pragma unroll
      for (int c = 0; c < 32; ++c) {
        if (pend & (1u << c)) {
          unsigned bad = ((unsigned)vv[c][0] ^ eps) & 1u;
          bad |= ((unsigned)(vv[c][0] >> 32) ^ eps) & 1u;
          bad |= ((unsigned)vv[c][1] ^ eps) & 1u;
          bad |= ((unsigned)(vv[c][1] >> 32) ^ eps) & 1u;
          if (__all(bad == 0u)) { DO_CHUNK(c, vv[c]); pend &= ~(1u << c); }
        }
      }
      if (++iters > (1 << 15)) break;   // safety valve: visible failure beats a hang
    }
#undef DO_CHUNK

    // ---- elementwise update directly on C layout: z[r][j] = ac[j][0]+ac[j][1] ----
    const f32x4 zj0 = ac[0][0] + ac[0][1];
    const f32x4 zj1 = ac[1][0] + ac[1][1];
    float hn[4][2];
#pragma unroll
    for (int r = 0; r < 4; ++r) {
      const float z0 = zj0[r] + w_c[r][0];
      const float z1 = zj1[r] + w_c[r][1];
      hn[r][0] = a_c[r][0] * hp[r][0] + b_c[r][0] * fast_tanh(z0);
      hn[r][1] = a_c[r][1] * hp[r][1] + b_c[r][1] * fast_tanh(z1);
    }

    // ---- publish immediately: pair channels via shfl_xor(1) ----
    if (t + 1 < T_STEPS) {
      const unsigned epn = (unsigned)(((t + 1) >> 1) & 1);
      unsigned* dst = hbp + (size_t)((t + 1) & 1) * 8192 + pbase;
#pragma unroll
      for (int r = 0; r < 4; ++r) {
        unsigned e0 = f2bf(hn[r][0]);
        unsigned e1 = f2bf(hn[r][1]);
        unsigned p0 = (unsigned)__shfl_xor((int)e0, 1);
        unsigned p1 = (unsigned)__shfl_xor((int)e1, 1);
        unsigned wv = jst ? ((e1 << 16) | ((p1 & 0xFFFEu) | epn))
                          : ((p0 << 16) | ((e0 & 0xFFFEu) | epn));
        __hip_atomic_store(dst + r * 512, wv,
                           __ATOMIC_RELAXED, __HIP_MEMORY_SCOPE_AGENT);
      }
    }

#pragma unroll
    for (int r = 0; r < 4; ++r)
#pragma unroll
      for (int j = 0; j < 2; ++j) {
        dh[r][j] = hn[r][j]; hp[r][j] = hn[r][j];
        a_c[r][j] = a_n[r][j]; b_c[r][j] = b_n[r][j]; w_c[r][j] = w_n[r][j];
      }
  }

  // ---- flush final step's outputs ----
  {
    const long od = (long)(T_STEPS - 1) * BD + gbase;
#pragma unroll
    for (int r = 0; r < 4; ++r)
#pragma unroll
      for (int j = 0; j < 2; ++j) {
        const long oo = od + r * 1024 + j * 16;
        const float d = dh[r][j];
        __builtin_nontemporal_store(d, h_out + BD + oo);
        const float sg = 1.0f / (1.0f + __expf(-d));
        __builtin_nontemporal_store(d * d * sg, out_buf + oo);
      }
  }
}

// ---------------- launch ----------------
extern "C" void kernel_launch(void* const* d_in, const int* in_sizes, int n_in,
                              void* d_out, int out_size, void* d_ws, size_t ws_size,
                              hipStream_t stream) {
  const float* x  = (const float*)d_in[0];
  const float* h0 = (const float*)d_in[1];
  const float* Wa = (const float*)d_in[2];
  const float* ba = (const float*)d_in[3];
  const float* Wb = (const float*)d_in[4];
  const float* bb = (const float*)d_in[5];
  const float* Wh = (const float*)d_in[6];
  const float* Wx = (const float*)d_in[7];
  const float* bx = (const float*)d_in[8];

  float* out_buf = (float*)d_out;
  float* h_out   = out_buf + OUT_ELEMS;

  char* ws = (char*)d_ws;
  float*          wx_buf = (float*)(ws + WX_OFF);
  unsigned short* xbf    = (unsigned short*)(ws + XBF_OFF);
  unsigned short* whi    = (unsigned short*)(ws + WHI_OFF);
  unsigned short* wlo    = (unsigned short*)(ws + WLO_OFF);
  unsigned*       hbp    = (unsigned*)(ws + HBP_OFF);

  // 0xFF => epoch bit 1 in every word: reads as STALE for t=0 (eps 0).
  hipMemsetAsync(hbp, 0xFF, 65536, stream);
  convert_x_kernel<<<4096, 256, 0, stream>>>(x, xbf);
  convert_w_kernel<<<1024, 256, 0, stream>>>(Wa, Wb, Wx, whi, wlo);
  gemm_pre<<<dim3(256, 24), 256, 0, stream>>>(xbf, whi, wlo, ba, bb, bx,
                                              h_out + BD, out_buf, wx_buf);
  scan_kernel<<<32, 256, 0, stream>>>(Wh, h0, wx_buf, out_buf, h_out, hbp);
}

// Round 14
// 8218.328 us; speedup vs baseline: 2.4961x; 2.4961x over previous
//
#include <hip/hip_runtime.h>
#include <stdint.h>
#include <stddef.h>

// ---------------- problem constants ----------------
static constexpr int  T_STEPS   = 2048;
static constexpr int  BATCH     = 16;
static constexpr int  DIM       = 1024;
static constexpr long RROWS     = (long)T_STEPS * BATCH;   // 32768 rows of x
static constexpr long BD        = (long)BATCH * DIM;       // 16384
static constexpr long OUT_ELEMS = (long)T_STEPS * BD;      // 33554432

// ---------------- ws layout (bytes) ----------------
static constexpr size_t WX_OFF  = 0;
static constexpr size_t XBF_OFF = 134217728;
static constexpr size_t WHI_OFF = XBF_OFF + 67108864;   // 201326592
static constexpr size_t WLO_OFF = WHI_OFF + 6291456;    // 207618048
static constexpr size_t HBP_OFF = WLO_OFF + 6291456;    // 213909504: packed h [2][B][D/2] u32 (64KB)

typedef __attribute__((ext_vector_type(2))) float          f32x2;
typedef __attribute__((ext_vector_type(4))) float          f32x4;
typedef __attribute__((ext_vector_type(8))) short          s16x8;
typedef __attribute__((ext_vector_type(4))) unsigned short u16x4;
typedef __attribute__((ext_vector_type(8))) unsigned short u16x8;

#define AS1 __attribute__((address_space(1)))
#define AS3 __attribute__((address_space(3)))

// ---------------- helpers ----------------
static __device__ __forceinline__ unsigned short f2bf(float x) {
  union { float f; unsigned u; } a; a.f = x;
  unsigned r = a.u + 0x7fffu + ((a.u >> 16) & 1u);
  return (unsigned short)(r >> 16);
}
static __device__ __forceinline__ float bf2f(unsigned short h) {
  union { unsigned u; float f; } a; a.u = ((unsigned)h) << 16; return a.f;
}
static __device__ __forceinline__ void gload_lds16(const void* g, void* l) {
  __builtin_amdgcn_global_load_lds((const AS1 void*)g, (AS3 void*)l, 16, 0, 0);
}
static __device__ __forceinline__ float fast_tanh(float z) {
  return 1.0f - 2.0f / (__expf(2.0f * z) + 1.0f);
}

// ---------------- convert x -> bf16 ----------------
__global__ __launch_bounds__(256) void convert_x_kernel(const float* __restrict__ x,
                                                        unsigned short* __restrict__ xbf) {
  const long n8 = (RROWS * DIM) / 8;
  const long stride = (long)gridDim.x * blockDim.x;
  for (long i = (long)blockIdx.x * blockDim.x + threadIdx.x; i < n8; i += stride) {
    const float4* p = (const float4*)(x + i * 8);
    float4 v0 = p[0], v1 = p[1];
    u16x8 o;
    o[0] = f2bf(v0.x); o[1] = f2bf(v0.y); o[2] = f2bf(v0.z); o[3] = f2bf(v0.w);
    o[4] = f2bf(v1.x); o[5] = f2bf(v1.y); o[6] = f2bf(v1.z); o[7] = f2bf(v1.w);
    *(u16x8*)(xbf + i * 8) = o;
  }
}

// ---------------- convert [W_alpha;W_beta;W_x] -> bf16 hi/lo split ----------------
__global__ __launch_bounds__(256) void convert_w_kernel(const float* __restrict__ Wa,
                                                        const float* __restrict__ Wb,
                                                        const float* __restrict__ Wx,
                                                        unsigned short* __restrict__ whi,
                                                        unsigned short* __restrict__ wlo) {
  const long n4 = (3l * 1024 * 1024) / 4;
  const long stride = (long)gridDim.x * blockDim.x;
  for (long i = (long)blockIdx.x * blockDim.x + threadIdx.x; i < n4; i += stride) {
    long e = i * 4;
    int mat = (int)(e >> 20);
    long off = e & 1048575l;
    const float* src = (mat == 0) ? Wa : (mat == 1) ? Wb : Wx;
    float4 v = *(const float4*)(src + off);
    u16x4 hi, lo;
    hi[0] = f2bf(v.x); lo[0] = f2bf(v.x - bf2f(hi[0]));
    hi[1] = f2bf(v.y); lo[1] = f2bf(v.y - bf2f(hi[1]));
    hi[2] = f2bf(v.z); lo[2] = f2bf(v.z - bf2f(hi[2]));
    hi[3] = f2bf(v.w); lo[3] = f2bf(v.w - bf2f(hi[3]));
    *(u16x4*)(whi + e) = hi;
    *(u16x4*)(wlo + e) = lo;
  }
}

// ---------------- fused pre-GEMM: alpha/beta/wx = act(x @ Wcat^T + bias) ----------------
__global__ __launch_bounds__(256) void gemm_pre(
    const unsigned short* __restrict__ xbf,
    const unsigned short* __restrict__ whi,
    const unsigned short* __restrict__ wlo,
    const float* __restrict__ b_alpha, const float* __restrict__ b_beta, const float* __restrict__ b_x,
    float* __restrict__ alpha_dst, float* __restrict__ beta_dst, float* __restrict__ wx_dst)
{
  __shared__ unsigned short Al[128 * 64];
  __shared__ unsigned short Bh[128 * 64];
  __shared__ unsigned short Bl[128 * 64];
  const int tid  = threadIdx.x;
  const int lane = tid & 63;
  const int w    = tid >> 6;
  const int wm   = w >> 1, wn = w & 1;
  const long rowA0 = (long)blockIdx.x * 128;
  const int  colB0 = blockIdx.y * 128;

  f32x4 acc[4][4];
#pragma unroll
  for (int i = 0; i < 4; ++i)
#pragma unroll
    for (int j = 0; j < 4; ++j) acc[i][j] = (f32x4){0.f, 0.f, 0.f, 0.f};

  for (int k0 = 0; k0 < 1024; k0 += 64) {
#pragma unroll
    for (int is = 0; is < 4; ++is) {
      const int o   = is * 4096 + tid * 16;
      const int row = o >> 7;
      const int ke  = (o & 127) >> 1;
      const long asrc = (rowA0 + row) * 1024 + (k0 + ke);
      const long bsrc = ((long)(colB0 + row)) * 1024 + (k0 + ke);
      gload_lds16(xbf + asrc, (char*)Al + is * 4096 + w * 1024);
      gload_lds16(whi + bsrc, (char*)Bh + is * 4096 + w * 1024);
      gload_lds16(wlo + bsrc, (char*)Bl + is * 4096 + w * 1024);
    }
    asm volatile("s_waitcnt vmcnt(0)" ::: "memory");
    __syncthreads();
#pragma unroll
    for (int kk = 0; kk < 2; ++kk) {
      const int koff = kk * 64 + ((lane >> 4) * 16);
      s16x8 a[4], bhf[4], blf[4];
#pragma unroll
      for (int i = 0; i < 4; ++i)
        a[i] = *(const s16x8*)((const char*)Al + (wm * 64 + i * 16 + (lane & 15)) * 128 + koff);
#pragma unroll
      for (int j = 0; j < 4; ++j) {
        const int r = (wn * 64 + j * 16 + (lane & 15)) * 128 + koff;
        bhf[j] = *(const s16x8*)((const char*)Bh + r);
        blf[j] = *(const s16x8*)((const char*)Bl + r);
      }
#pragma unroll
      for (int i = 0; i < 4; ++i)
#pragma unroll
        for (int j = 0; j < 4; ++j) {
          acc[i][j] = __builtin_amdgcn_mfma_f32_16x16x32_bf16(a[i], bhf[j], acc[i][j], 0, 0, 0);
          acc[i][j] = __builtin_amdgcn_mfma_f32_16x16x32_bf16(a[i], blf[j], acc[i][j], 0, 0, 0);
        }
    }
    __syncthreads();
  }

  const int region = colB0 >> 10;
  const float* bias = (region == 0) ? b_alpha : (region == 1) ? b_beta : b_x;
  float* dst = (region == 0) ? alpha_dst : (region == 1) ? beta_dst : wx_dst;
#pragma unroll
  for (int j = 0; j < 4; ++j) {
    const int colg = colB0 + wn * 64 + j * 16 + (lane & 15);
    const int nl = colg & 1023;
    const float bj = bias[nl];
#pragma unroll
    for (int i = 0; i < 4; ++i) {
#pragma unroll
      for (int r = 0; r < 4; ++r) {
        const long rowg = rowA0 + wm * 64 + i * 16 + ((lane >> 4) * 4) + r;
        float z = acc[i][j][r] + bj;
        float val = (region == 2) ? z : (1.0f / (1.0f + __expf(-z)));
        dst[rowg * 1024 + nl] = val;
      }
    }
  }
}

// ---------------- persistent scan: packed-pair data-as-flag (round-12 structure) ----------------
// 32 WGs x 256 threads; WG owns channels [wg*32, wg*32+32).
// Wire word = {bf16(h[ch1]) << 16 | bf16(h[ch0]) with LSB = epoch bit (s>>1)&1},
// published into buf[s&1] via agent-scope RELAXED atomic stores. (buf, eps)
// discriminates s mod 4; data-dependency bounds WG drift to <4 steps. The
// packed word IS the MFMA A-fragment word -> zero unpack cost. 1MB/step wire
// traffic. Consumer wave w: chunk q <-> producer WG w*8+q; first sweep loads
// all 8 chunks branch-free; retry sweeps reload ONLY pending chunks in TWO
// HALVES (issue low, issue high, check low first): the low-half check's
// auto-waitcnt is a partial vmcnt wait, so early-arriving chunks MFMA while
// the younger half is still in flight. NT outputs deferred one iteration so
// HBM acks never gate sweep waits. hbp memset 0xFF per launch (stale for t=0).
__global__ __launch_bounds__(256, 1) void scan_kernel(
    const float* __restrict__ Wh,
    const float* __restrict__ h0,
    const float* __restrict__ wxb,
    float* __restrict__ out_buf,     // d_out: beta pre-stored here
    float* __restrict__ h_out,       // d_out + OUT_ELEMS: alpha pre-stored at +BD
    unsigned* __restrict__ hbp)      // packed h ping-pong [2][B][D/2] u32
{
  __shared__ unsigned short WhiL[32 * 1024];
  __shared__ unsigned short WloL[32 * 1024];
  __shared__ __align__(16) float zred[2][4][16][34];

  const int tid  = threadIdx.x;
  const int lane = tid & 63;
  const int w    = tid >> 6;
  const int wg   = blockIdx.x;
  const int n0   = wg * 32;

  // ---- stage W_h slice (32 rows) into LDS, hi/lo bf16, XOR-swizzled ----
  {
    const int row = tid >> 3;            // 0..31
    const int kb  = (tid & 7) * 128;     // 128 elems per thread
    const float* src = Wh + (size_t)(n0 + row) * 1024 + kb;
    const unsigned sx = ((unsigned)(row & 7)) << 4;
    const unsigned rb = (unsigned)row * 2048u;
#pragma unroll
    for (int q = 0; q < 32; ++q) {
      float4 v = *(const float4*)(src + q * 4);
      u16x4 hi, lo;
      hi[0] = f2bf(v.x); lo[0] = f2bf(v.x - bf2f(hi[0]));
      hi[1] = f2bf(v.y); lo[1] = f2bf(v.y - bf2f(hi[1]));
      hi[2] = f2bf(v.z); lo[2] = f2bf(v.z - bf2f(hi[2]));
      hi[3] = f2bf(v.w); lo[3] = f2bf(v.w - bf2f(hi[3]));
      const unsigned addr = (rb + (unsigned)(kb + q * 4) * 2u) ^ sx;
      *(u16x4*)((char*)WhiL + addr) = hi;
      *(u16x4*)((char*)WloL + addr) = lo;
    }
  }

  // elementwise ownership: thread owns (b_own, channels ch0=n0+2nl, ch1=ch0+1)
  const int b_own = tid >> 4;            // batch 0..15
  const int nl    = tid & 15;            // channel-pair id
  const long off0 = (long)b_own * 1024 + n0 + 2 * nl;   // +1 gives ch1
  const int  pword = b_own * 512 + wg * 16 + nl;        // word index within a buffer

  // MFMA operand roles
  const int arow = lane & 15;                      // A row (batch) / B col (channel)
  const int gk   = lane >> 4;                      // k subgroup
  const unsigned bswz = ((unsigned)(arow & 7)) << 4;

  // ---- phase 0: h[0] = h0, publish packed words (eps 0) into buf 0 ----
  f32x2 hpv = *(const f32x2*)(h0 + off0);
  float hp0 = hpv[0], hp1 = hpv[1];
  *(f32x2*)(h_out + off0) = hpv;
  {
    unsigned pv = ((unsigned)f2bf(hp1) << 16) | (unsigned)(f2bf(hp0) & 0xFFFEu);
    __hip_atomic_store(hbp + pword, pv, __ATOMIC_RELAXED, __HIP_MEMORY_SCOPE_AGENT);
  }
  __syncthreads();   // W LDS staging complete

  // gates for t=0 (alpha pre-stored in h[t+1] slots, beta in out[t] slots)
  f32x2 acv = *(const f32x2*)(h_out + BD + off0);
  f32x2 bcv = *(const f32x2*)(out_buf + off0);
  f32x2 wcv = *(const f32x2*)(wxb + off0);
  float a_c0 = acv[0], a_c1 = acv[1], b_c0 = bcv[0], b_c1 = bcv[1], w_c0 = wcv[0], w_c1 = wcv[1];

  // deferred NT-output state (step t's outputs stored during step t+1)
  float dh0 = 0.f, dh1 = 0.f;

  for (int t = 0; t < T_STEPS; ++t) {
    const unsigned eps = (unsigned)((t >> 1) & 1);
    // per-lane u64 base: buf (t&1), row arow, wave k-quarter, k-subgroup gk
    const unsigned long long* base64 =
        (const unsigned long long*)hbp +
        (((size_t)(t & 1) * 8192 + (long)arow * 512 + w * 128 + gk * 4) >> 1);

    // ---- first sweep: issue ALL chunk loads branch-free (2 u64/chunk) ----
    unsigned long long vv[8][2];
#pragma unroll
    for (int q = 0; q < 8; ++q) {
      vv[q][0] = __hip_atomic_load(base64 + q * 8,     __ATOMIC_RELAXED, __HIP_MEMORY_SCOPE_AGENT);
      vv[q][1] = __hip_atomic_load(base64 + q * 8 + 1, __ATOMIC_RELAXED, __HIP_MEMORY_SCOPE_AGENT);
    }

    // prefetch next step's gates (NT loads; younger than sweeps)
    float a_n0 = 0.f, a_n1 = 0.f, b_n0 = 0.f, b_n1 = 0.f, w_n0 = 0.f, w_n1 = 0.f;
    if (t + 1 < T_STEPS) {
      const long o = (long)(t + 1) * BD + off0;
      f32x2 an = __builtin_nontemporal_load((const f32x2*)(h_out + BD + o));
      f32x2 bn = __builtin_nontemporal_load((const f32x2*)(out_buf + o));
      f32x2 wn = __builtin_nontemporal_load((const f32x2*)(wxb + o));
      a_n0 = an[0]; a_n1 = an[1]; b_n0 = bn[0]; b_n1 = bn[1]; w_n0 = wn[0]; w_n1 = wn[1];
    }
    __builtin_amdgcn_sched_barrier(0);

    // ---- deferred NT output stores for step t-1 (youngest vmem ops) ----
    if (t > 0) {
      const long od = (long)(t - 1) * BD + off0;
      f32x2 hv; hv[0] = dh0; hv[1] = dh1;
      __builtin_nontemporal_store(hv, (f32x2*)(h_out + BD + od));
      const float sg0 = 1.0f / (1.0f + __expf(-dh0));
      const float sg1 = 1.0f / (1.0f + __expf(-dh1));
      f32x2 ov; ov[0] = dh0 * dh0 * sg0; ov[1] = dh1 * dh1 * sg1;
      __builtin_nontemporal_store(ov, (f32x2*)(out_buf + od));
    }

    f32x4 acc0 = (f32x4){0.f,0.f,0.f,0.f};
    f32x4 acc1 = (f32x4){0.f,0.f,0.f,0.f};
    const unsigned kbase = (unsigned)(w * 256 + gk * 8) * 2u;   // byte offset in W row
    union Frag { unsigned long long u[2]; s16x8 h; };

#define DO_CHUNK(Q, V)                                                          \
    {                                                                           \
      Frag fh; fh.u[0] = (V)[0]; fh.u[1] = (V)[1];                              \
      const unsigned kb = kbase + (unsigned)(Q) * 64u;                          \
      const unsigned a0 = ((unsigned)arow * 2048u + kb) ^ bswz;                 \
      const unsigned a1 = ((unsigned)(16 + arow) * 2048u + kb) ^ bswz;          \
      s16x8 bh0 = *(const s16x8*)((const char*)WhiL + a0);                      \
      s16x8 bl0 = *(const s16x8*)((const char*)WloL + a0);                      \
      s16x8 bh1 = *(const s16x8*)((const char*)WhiL + a1);                      \
      s16x8 bl1 = *(const s16x8*)((const char*)WloL + a1);                      \
      acc0 = __builtin_amdgcn_mfma_f32_16x16x32_bf16(fh.h, bh0, acc0, 0, 0, 0); \
      acc0 = __builtin_amdgcn_mfma_f32_16x16x32_bf16(fh.h, bl0, acc0, 0, 0, 0); \
      acc1 = __builtin_amdgcn_mfma_f32_16x16x32_bf16(fh.h, bh1, acc1, 0, 0, 0); \
      acc1 = __builtin_amdgcn_mfma_f32_16x16x32_bf16(fh.h, bl1, acc1, 0, 0, 0); \
    }

    // ---- verify (epoch bit on even-channel words) + MFMA fresh chunks ----
    unsigned pend = 0;
#pragma unroll
    for (int q = 0; q < 8; ++q) {
      unsigned bad = 0;
#pragma unroll
      for (int d = 0; d < 2; ++d) {
        bad |= ((unsigned)vv[q][d] ^ eps) & 1u;
        bad |= ((unsigned)(vv[q][d] >> 32) ^ eps) & 1u;
      }
      if (__all(bad == 0u)) { DO_CHUNK(q, vv[q]); }
      else                  { pend |= 1u << q; }
    }

    // ---- retry sweeps: pending-only, issued in TWO HALVES; checking the low
    //      half first means its auto-waitcnt is a PARTIAL vmcnt wait (the
    //      high-half loads are younger) -> early chunks MFMA sooner ----
    int iters = 0;
    while (pend) {
#pragma unroll
      for (int q = 0; q < 4; ++q)
        if (pend & (1u << q)) {
          vv[q][0] = __hip_atomic_load(base64 + q * 8,     __ATOMIC_RELAXED, __HIP_MEMORY_SCOPE_AGENT);
          vv[q][1] = __hip_atomic_load(base64 + q * 8 + 1, __ATOMIC_RELAXED, __HIP_MEMORY_SCOPE_AGENT);
        }
#pragma unroll
      for (int q = 4; q < 8; ++q)
        if (pend & (1u << q)) {
          vv[q][0] = __hip_atomic_load(base64 + q * 8,     __ATOMIC_RELAXED, __HIP_MEMORY_SCOPE_AGENT);
          vv[q][1] = __hip_atomic_load(base64 + q * 8 + 1, __ATOMIC_RELAXED, __HIP_MEMORY_SCOPE_AGENT);
        }
      __builtin_amdgcn_sched_barrier(0);   // keep issue-phase and check-phase apart
#pragma unroll
      for (int q = 0; q < 4; ++q) {        // low half first: partial vmcnt wait
        if (pend & (1u << q)) {
          unsigned bad = 0;
#pragma unroll
          for (int d = 0; d < 2; ++d) {
            bad |= ((unsigned)vv[q][d] ^ eps) & 1u;
            bad |= ((unsigned)(vv[q][d] >> 32) ^ eps) & 1u;
          }
          if (__all(bad == 0u)) { DO_CHUNK(q, vv[q]); pend &= ~(1u << q); }
        }
      }
#pragma unroll
      for (int q = 4; q < 8; ++q) {
        if (pend & (1u << q)) {
          unsigned bad = 0;
#pragma unroll
          for (int d = 0; d < 2; ++d) {
            bad |= ((unsigned)vv[q][d] ^ eps) & 1u;
            bad |= ((unsigned)(vv[q][d] >> 32) ^ eps) & 1u;
          }
          if (__all(bad == 0u)) { DO_CHUNK(q, vv[q]); pend &= ~(1u << q); }
        }
      }
      if (++iters > (1 << 15)) break;   // safety valve: visible failure beats a hang
    }
#undef DO_CHUNK

    // ---- cross-wave K reduction via LDS ----
    const int tb = t & 1;
#pragma unroll
    for (int r = 0; r < 4; ++r) {
      zred[tb][w][gk * 4 + r][arow]      = acc0[r];
      zred[tb][w][gk * 4 + r][16 + arow] = acc1[r];
    }
    __syncthreads();   // the only per-step barrier (zred double-buffered)

    // ---- elementwise update for (b_own, ch0) and (b_own, ch1) ----
    float z0 = w_c0, z1 = w_c1;
#pragma unroll
    for (int wv = 0; wv < 4; ++wv) {
      f32x2 p = *(const f32x2*)&zred[tb][wv][b_own][2 * nl];
      z0 += p[0]; z1 += p[1];
    }
    const float v0 = fast_tanh(z0), v1 = fast_tanh(z1);
    const float hn0 = a_c0 * hp0 + b_c0 * v0;
    const float hn1 = a_c1 * hp1 + b_c1 * v1;

    // publish immediately (earliest visibility) — one u32, agent-scope atomic
    if (t + 1 < T_STEPS) {
      const unsigned epn = (unsigned)(((t + 1) >> 1) & 1);
      unsigned pv = ((unsigned)f2bf(hn1) << 16)
                  | (unsigned)((f2bf(hn0) & 0xFFFEu) | epn);
      __hip_atomic_store(hbp + ((size_t)((t + 1) & 1) * 8192 + pword), pv,
                         __ATOMIC_RELAXED, __HIP_MEMORY_SCOPE_AGENT);
    }

    // outputs for this step are deferred to next iteration (or flushed below)
    dh0 = hn0; dh1 = hn1;
    hp0 = hn0; hp1 = hn1;
    a_c0 = a_n0; a_c1 = a_n1; b_c0 = b_n0; b_c1 = b_n1; w_c0 = w_n0; w_c1 = w_n1;
  }

  // ---- flush final step's outputs ----
  {
    const long od = (long)(T_STEPS - 1) * BD + off0;
    f32x2 hv; hv[0] = dh0; hv[1] = dh1;
    __builtin_nontemporal_store(hv, (f32x2*)(h_out + BD + od));
    const float sg0 = 1.0f / (1.0f + __expf(-dh0));
    const float sg1 = 1.0f / (1.0f + __expf(-dh1));
    f32x2 ov; ov[0] = dh0 * dh0 * sg0; ov[1] = dh1 * dh1 * sg1;
    __builtin_nontemporal_store(ov, (f32x2*)(out_buf + od));
  }
}

// ---------------- launch ----------------
extern "C" void kernel_launch(void* const* d_in, const int* in_sizes, int n_in,
                              void* d_out, int out_size, void* d_ws, size_t ws_size,
                              hipStream_t stream) {
  const float* x  = (const float*)d_in[0];
  const float* h0 = (const float*)d_in[1];
  const float* Wa = (const float*)d_in[2];
  const float* ba = (const float*)d_in[3];
  const float* Wb = (const float*)d_in[4];
  const float* bb = (const float*)d_in[5];
  const float* Wh = (const float*)d_in[6];
  const float* Wx = (const float*)d_in[7];
  const float* bx = (const float*)d_in[8];

  float* out_buf = (float*)d_out;
  float* h_out   = out_buf + OUT_ELEMS;

  char* ws = (char*)d_ws;
  float*          wx_buf = (float*)(ws + WX_OFF);
  unsigned short* xbf    = (unsigned short*)(ws + XBF_OFF);
  unsigned short* whi    = (unsigned short*)(ws + WHI_OFF);
  unsigned short* wlo    = (unsigned short*)(ws + WLO_OFF);
  unsigned*       hbp    = (unsigned*)(ws + HBP_OFF);

  // 0xFF => epoch bit 1 in every word: reads as STALE for t=0 (eps 0).
  hipMemsetAsync(hbp, 0xFF, 65536, stream);
  convert_x_kernel<<<4096, 256, 0, stream>>>(x, xbf);
  convert_w_kernel<<<1024, 256, 0, stream>>>(Wa, Wb, Wx, whi, wlo);
  gemm_pre<<<dim3(256, 24), 256, 0, stream>>>(xbf, whi, wlo, ba, bb, bx,
                                              h_out + BD, out_buf, wx_buf);
  scan_kernel<<<32, 256, 0, stream>>>(Wh, h0, wx_buf, out_buf, h_out, hbp);
}